// Round 1
// baseline (134.543 us; speedup 1.0000x reference)
//
#include <hip/hip_runtime.h>

// Problem constants (from reference): B=4, Q=512, P=512, Q_SIZE=512, P_SIZE=512, V_SIZE=256
#define BQ_ROWS 2048      // B*Q rows of hq (also B*P rows of hp)
#define KDIM    512
#define VDIM    256
#define DDIM    512

// ---------------------------------------------------------------------------
// Kernel 1: projections  sq = hq @ W1  (2048x512 @ 512x256),  sp = hp @ W2
// Tiled f32 GEMM: 64x64 tile, BK=16, 256 threads, 4x4 per thread.
// ---------------------------------------------------------------------------
#define BM 64
#define BN 64
#define BK 16

__global__ __launch_bounds__(256) void proj_gemm(
    const float* __restrict__ hq, const float* __restrict__ hp,
    const float* __restrict__ W1, const float* __restrict__ W2,
    float* __restrict__ sq, float* __restrict__ sp)
{
    const int K = KDIM, N = VDIM;
    const int by = blockIdx.y;            // 0..63 : first 32 -> sq, last 32 -> sp
    const float *A, *W;
    float *C;
    int m0;
    if (by < 32) { A = hq; W = W1; C = sq; m0 = by * BM; }
    else         { A = hp; W = W2; C = sp; m0 = (by - 32) * BM; }
    const int n0 = blockIdx.x * BN;

    __shared__ float As[BK][BM + 4];      // [k][m] (transposed)
    __shared__ float Bs[BK][BN + 4];      // [k][n]

    const int tid  = threadIdx.x;
    const int tr   = tid >> 4;            // 0..15 -> rows tr*4..+3
    const int tc   = tid & 15;            // 0..15 -> cols tc*4..+3
    const int la_r = tid >> 2;            // 0..63
    const int la_c = (tid & 3) << 2;      // 0,4,8,12
    const int lb_r = tid >> 4;            // 0..15
    const int lb_c = (tid & 15) << 2;     // 0..60

    float acc[4][4];
    #pragma unroll
    for (int i = 0; i < 4; ++i)
        #pragma unroll
        for (int j = 0; j < 4; ++j) acc[i][j] = 0.f;

    for (int k0 = 0; k0 < K; k0 += BK) {
        float4 a4 = *(const float4*)(A + (size_t)(m0 + la_r) * K + k0 + la_c);
        float4 b4 = *(const float4*)(W + (size_t)(k0 + lb_r) * N + n0 + lb_c);
        __syncthreads();
        As[la_c + 0][la_r] = a4.x;
        As[la_c + 1][la_r] = a4.y;
        As[la_c + 2][la_r] = a4.z;
        As[la_c + 3][la_r] = a4.w;
        *(float4*)(&Bs[lb_r][lb_c]) = b4;
        __syncthreads();
        #pragma unroll
        for (int kk = 0; kk < BK; ++kk) {
            float4 av = *(const float4*)(&As[kk][tr << 2]);
            float4 bv = *(const float4*)(&Bs[kk][tc << 2]);
            const float* ap = (const float*)&av;
            const float* bp = (const float*)&bv;
            #pragma unroll
            for (int i = 0; i < 4; ++i)
                #pragma unroll
                for (int j = 0; j < 4; ++j)
                    acc[i][j] = fmaf(ap[i], bp[j], acc[i][j]);
        }
    }
    #pragma unroll
    for (int i = 0; i < 4; ++i) {
        float4 r = make_float4(acc[i][0], acc[i][1], acc[i][2], acc[i][3]);
        *(float4*)(C + (size_t)(m0 + (tr << 2) + i) * N + n0 + (tc << 2)) = r;
    }
}

// ---------------------------------------------------------------------------
// Kernel 2: per block: 4 p-rows of one batch.
//  phase 1: s[p,q] = sum_v tanh(sp[p,v]+sq[q,v])*v[v]   (thread owns 2 q's)
//  phase 2: softmax over q (one wave per p-row)
//  phase 3: out[p,:] = sum_q a[p,q] * hq[q,:]           (thread owns 2 d's)
// tanh(x) = 1 - 2/(1+exp(2x)); exp(2x) = exp2(x * 2*log2(e)).
// sp is pre-scaled by 2*log2(e) at LDS load so the inner loop is
// add -> exp2 -> add -> rcp -> fma -> fma (4 VALU + 2 trans per tanh).
// ---------------------------------------------------------------------------
#define TWO_LOG2E 2.8853900817779268f
#define LOG2E     1.4426950408889634f

__global__ __launch_bounds__(256) void attn_kernel(
    const float* __restrict__ hq, const float* __restrict__ sq,
    const float* __restrict__ sp, const float* __restrict__ vvec,
    float* __restrict__ out)
{
    const int blk = blockIdx.x;          // 0..511
    const int b   = blk >> 7;            // 0..3
    const int p0  = (blk & 127) << 2;    // 0,4,...,508

    __shared__ float sp_s[4][VDIM];      // pre-scaled by 2*log2(e)
    __shared__ float vv_s[VDIM];
    __shared__ float score[4][512];

    const int t = threadIdx.x;           // 0..255

    vv_s[t] = vvec[t];
    #pragma unroll
    for (int pp = 0; pp < 4; ++pp)
        sp_s[pp][t] = sp[(size_t)((b << 9) + p0 + pp) * VDIM + t] * TWO_LOG2E;
    __syncthreads();

    // ---- phase 1: scores ----
    float acc[2][4];
    #pragma unroll
    for (int qi = 0; qi < 2; ++qi)
        #pragma unroll
        for (int pp = 0; pp < 4; ++pp) acc[qi][pp] = 0.f;

    #pragma unroll
    for (int qi = 0; qi < 2; ++qi) {
        const int q = t + (qi << 8);
        const float4* row = (const float4*)(sq + (size_t)((b << 9) + q) * VDIM);
        #pragma unroll 2
        for (int vi = 0; vi < VDIM / 4; ++vi) {
            float4 s4 = row[vi];
            const float* sv = (const float*)&s4;
            #pragma unroll
            for (int j = 0; j < 4; ++j) {
                const float svc = sv[j] * TWO_LOG2E;
                const float vj  = vv_s[(vi << 2) + j];
                #pragma unroll
                for (int pp = 0; pp < 4; ++pp) {
                    float e  = __builtin_amdgcn_exp2f(sp_s[pp][(vi << 2) + j] + svc);
                    float r  = __builtin_amdgcn_rcpf(1.f + e);
                    float th = fmaf(-2.f, r, 1.f);          // tanh
                    acc[qi][pp] = fmaf(vj, th, acc[qi][pp]);
                }
            }
        }
    }
    #pragma unroll
    for (int pp = 0; pp < 4; ++pp) {
        score[pp][t]       = acc[0][pp];
        score[pp][t + 256] = acc[1][pp];
    }
    __syncthreads();

    // ---- phase 2: softmax over q, one wave per p-row ----
    {
        const int pp   = t >> 6;         // wave id = p-row
        const int lane = t & 63;
        float vals[8];
        float m = -1e30f;
        #pragma unroll
        for (int i = 0; i < 8; ++i) {
            vals[i] = score[pp][lane + (i << 6)];
            m = fmaxf(m, vals[i]);
        }
        #pragma unroll
        for (int off = 32; off; off >>= 1) m = fmaxf(m, __shfl_xor(m, off));
        float sum = 0.f;
        #pragma unroll
        for (int i = 0; i < 8; ++i) {
            vals[i] = __builtin_amdgcn_exp2f((vals[i] - m) * LOG2E);
            sum += vals[i];
        }
        #pragma unroll
        for (int off = 32; off; off >>= 1) sum += __shfl_xor(sum, off);
        const float inv = __builtin_amdgcn_rcpf(sum);
        #pragma unroll
        for (int i = 0; i < 8; ++i) score[pp][lane + (i << 6)] = vals[i] * inv;
    }
    __syncthreads();

    // ---- phase 3: out[p, :] = sum_q a[p,q] * hq[q, :] ----
    float ax[4], ay[4];
    #pragma unroll
    for (int pp = 0; pp < 4; ++pp) { ax[pp] = 0.f; ay[pp] = 0.f; }

    const float2* hq2 = (const float2*)hq;
    #pragma unroll 4
    for (int q = 0; q < 512; ++q) {
        float2 h2 = hq2[((size_t)((b << 9) + q) << 8) + t];
        #pragma unroll
        for (int pp = 0; pp < 4; ++pp) {
            const float a = score[pp][q];
            ax[pp] = fmaf(a, h2.x, ax[pp]);
            ay[pp] = fmaf(a, h2.y, ay[pp]);
        }
    }
    #pragma unroll
    for (int pp = 0; pp < 4; ++pp) {
        float2 r = make_float2(ax[pp], ay[pp]);
        *(float2*)(out + (size_t)((b << 9) + p0 + pp) * DDIM + (t << 1)) = r;
    }
}

// ---------------------------------------------------------------------------
extern "C" void kernel_launch(void* const* d_in, const int* in_sizes, int n_in,
                              void* d_out, int out_size, void* d_ws, size_t ws_size,
                              hipStream_t stream)
{
    const float* hq = (const float*)d_in[0];   // [4,512,512]
    const float* hp = (const float*)d_in[1];   // [4,512,512]
    const float* W1 = (const float*)d_in[2];   // [512,256]
    const float* W2 = (const float*)d_in[3];   // [512,256]
    const float* vv = (const float*)d_in[4];   // [256]
    float* out = (float*)d_out;                // [4,512,512]

    float* sq = (float*)d_ws;                  // [2048,256]
    float* sp = sq + (size_t)BQ_ROWS * VDIM;   // [2048,256]

    dim3 g1(VDIM / BN, 2 * (BQ_ROWS / BM));    // 4 x 64
    proj_gemm<<<g1, 256, 0, stream>>>(hq, hp, W1, W2, sq, sp);

    attn_kernel<<<512, 256, 0, stream>>>(hq, sq, sp, vv, out);
}

// Round 2
// 92.708 us; speedup vs baseline: 1.4513x; 1.4513x over previous
//
#include <hip/hip_runtime.h>

// B=4, Q=512, P=512, Q_SIZE=512 (=DDIM), P_SIZE=512, V_SIZE=256 (=VDIM)
#define VDIM 256
#define DDIM 512
#define LOG2E     1.4426950408889634f
#define TWO_LOG2E 2.8853900817779268f

// ---------------------------------------------------------------------------
// K1: projections fused with exp:  Eq = exp(2*(hq@W1)),  Ep = exp(2*(hp@W2))
// 32x64 tile, BK=16, 256 threads, 2x4 acc/thread. grid = (4, 128).
// ---------------------------------------------------------------------------
__global__ __launch_bounds__(256) void proj_exp_gemm(
    const float* __restrict__ hq, const float* __restrict__ hp,
    const float* __restrict__ W1, const float* __restrict__ W2,
    float* __restrict__ Eq, float* __restrict__ Ep)
{
    const int by = blockIdx.y;            // 0..127: first 64 -> Eq, last 64 -> Ep
    const float *A, *W; float *C;
    if (by < 64) { A = hq; W = W1; C = Eq; }
    else         { A = hp; W = W2; C = Ep; }
    const int m0 = (by & 63) * 32;
    const int n0 = blockIdx.x * 64;

    __shared__ __attribute__((aligned(16))) float As[16][36];   // [k][m]
    __shared__ __attribute__((aligned(16))) float Bs[16][68];   // [k][n]

    const int tid  = threadIdx.x;
    const int tr   = tid >> 4;            // 0..15 -> rows tr*2..+1
    const int tc   = tid & 15;            // 0..15 -> cols tc*4..+3
    const int la_r = tid >> 3;            // 0..31
    const int la_c = (tid & 7) << 1;      // 0,2,..,14
    const int lb_r = tid >> 4;            // 0..15
    const int lb_c = (tid & 15) << 2;     // 0..60

    float acc[2][4] = {};

    for (int k0 = 0; k0 < 512; k0 += 16) {
        float2 a2 = *(const float2*)(A + (size_t)(m0 + la_r) * 512 + k0 + la_c);
        float4 b4 = *(const float4*)(W + (size_t)(k0 + lb_r) * VDIM + n0 + lb_c);
        __syncthreads();
        As[la_c + 0][la_r] = a2.x;
        As[la_c + 1][la_r] = a2.y;
        *(float4*)&Bs[lb_r][lb_c] = b4;
        __syncthreads();
        #pragma unroll
        for (int kk = 0; kk < 16; ++kk) {
            float2 av = *(const float2*)&As[kk][tr << 1];
            float4 bv = *(const float4*)&Bs[kk][tc << 2];
            const float* ap = (const float*)&av;
            const float* bp = (const float*)&bv;
            #pragma unroll
            for (int i = 0; i < 2; ++i)
                #pragma unroll
                for (int j = 0; j < 4; ++j)
                    acc[i][j] = fmaf(ap[i], bp[j], acc[i][j]);
        }
    }
    #pragma unroll
    for (int i = 0; i < 2; ++i) {
        float4 r;
        r.x = __builtin_amdgcn_exp2f(acc[i][0] * TWO_LOG2E);
        r.y = __builtin_amdgcn_exp2f(acc[i][1] * TWO_LOG2E);
        r.z = __builtin_amdgcn_exp2f(acc[i][2] * TWO_LOG2E);
        r.w = __builtin_amdgcn_exp2f(acc[i][3] * TWO_LOG2E);
        *(float4*)(C + (size_t)(m0 + (tr << 1) + i) * VDIM + n0 + (tc << 2)) = r;
    }
}

// ---------------------------------------------------------------------------
// K2: block = (b, 4 p-rows). Scores via tanh(x)=1-2/(1+e^{2x}) with
// e^{2(sp+sq)} = Ep*Eq (1 rcp + 2 fma per term). Constant sum(v) cancels in
// softmax, so score stored as raw acc and negated/scaled in softmax.
// FUSED=false: writes softmaxed a[b,p,q] to aout (out_gemm does phase 3).
// FUSED=true : does phase 3 inline (fallback for small workspace).
// ---------------------------------------------------------------------------
template<bool FUSED>
__global__ __launch_bounds__(256) void score_softmax(
    const float* __restrict__ Eq, const float* __restrict__ Ep,
    const float* __restrict__ vvec, const float* __restrict__ hq,
    float* __restrict__ aout, float* __restrict__ out)
{
    const int blk = blockIdx.x;           // 0..511
    const int b   = blk >> 7;
    const int p0  = (blk & 127) << 2;

    __shared__ __attribute__((aligned(16))) float ep_s[4][VDIM];
    __shared__ __attribute__((aligned(16))) float vv_s[VDIM];
    __shared__ __attribute__((aligned(16))) float score[4][512];

    const int t = threadIdx.x;            // 0..255

    vv_s[t] = vvec[t];
    #pragma unroll
    for (int pp = 0; pp < 4; ++pp)
        ep_s[pp][t] = Ep[(size_t)((b << 9) + p0 + pp) * VDIM + t];
    __syncthreads();

    // ---- phase 1: acc[q-half][pp] = sum_v v_j / (1 + Ep*Eq) ----
    float acc0[4] = {}, acc1[4] = {};
    const float4* eq0 = (const float4*)(Eq + (size_t)((b << 9) + t) * VDIM);
    const float4* eq1 = (const float4*)(Eq + (size_t)((b << 9) + t + 256) * VDIM);

    #pragma unroll 2
    for (int vi = 0; vi < VDIM / 4; ++vi) {
        float4 e0 = eq0[vi];
        float4 e1 = eq1[vi];
        float4 w4 = *(const float4*)&vv_s[vi << 2];
        float4 p4[4];
        #pragma unroll
        for (int pp = 0; pp < 4; ++pp) p4[pp] = *(const float4*)&ep_s[pp][vi << 2];
        const float* e0f = (const float*)&e0;
        const float* e1f = (const float*)&e1;
        const float* wf  = (const float*)&w4;
        #pragma unroll
        for (int j = 0; j < 4; ++j) {
            #pragma unroll
            for (int pp = 0; pp < 4; ++pp) {
                const float pj = ((const float*)&p4[pp])[j];
                const float r0 = __builtin_amdgcn_rcpf(fmaf(pj, e0f[j], 1.f));
                const float r1 = __builtin_amdgcn_rcpf(fmaf(pj, e1f[j], 1.f));
                acc0[pp] = fmaf(wf[j], r0, acc0[pp]);
                acc1[pp] = fmaf(wf[j], r1, acc1[pp]);
            }
        }
    }
    #pragma unroll
    for (int pp = 0; pp < 4; ++pp) {
        score[pp][t]       = acc0[pp];
        score[pp][t + 256] = acc1[pp];
    }
    __syncthreads();

    // ---- phase 2: softmax over q (true score = const - 2*acc) ----
    {
        const int pp = t >> 6, lane = t & 63;
        float vals[8];
        float m = -1e30f;
        #pragma unroll
        for (int i = 0; i < 8; ++i) {
            vals[i] = -2.f * score[pp][lane + (i << 6)];
            m = fmaxf(m, vals[i]);
        }
        #pragma unroll
        for (int off = 32; off; off >>= 1) m = fmaxf(m, __shfl_xor(m, off));
        float sum = 0.f;
        #pragma unroll
        for (int i = 0; i < 8; ++i) {
            vals[i] = __builtin_amdgcn_exp2f((vals[i] - m) * LOG2E);
            sum += vals[i];
        }
        #pragma unroll
        for (int off = 32; off; off >>= 1) sum += __shfl_xor(sum, off);
        const float inv = __builtin_amdgcn_rcpf(sum);
        #pragma unroll
        for (int i = 0; i < 8; ++i) score[pp][lane + (i << 6)] = vals[i] * inv;
    }
    __syncthreads();

    if (!FUSED) {
        // write a[b, p0+pp, :] (float4-coalesced)
        const int pp = t >> 6, c = t & 63;
        float4* arow = (float4*)(aout + (size_t)((b << 9) + p0 + pp) * 512);
        arow[c]      = *(const float4*)&score[pp][c << 2];
        arow[c + 64] = *(const float4*)&score[pp][(c + 64) << 2];
    } else {
        // fallback phase 3: out[p,:] = sum_q a[p,q] * hq[q,:]
        float ax[4] = {}, ay[4] = {};
        const float2* hq2 = (const float2*)hq;
        #pragma unroll 4
        for (int q = 0; q < 512; ++q) {
            float2 h2 = hq2[((size_t)((b << 9) + q) << 8) + t];
            #pragma unroll
            for (int pp = 0; pp < 4; ++pp) {
                const float a = score[pp][q];
                ax[pp] = fmaf(a, h2.x, ax[pp]);
                ay[pp] = fmaf(a, h2.y, ay[pp]);
            }
        }
        #pragma unroll
        for (int pp = 0; pp < 4; ++pp) {
            float2 r = make_float2(ax[pp], ay[pp]);
            *(float2*)(out + (size_t)((b << 9) + p0 + pp) * DDIM + (t << 1)) = r;
        }
    }
}

// ---------------------------------------------------------------------------
// K3: out[b] = a[b] @ hq[b]   (512x512 @ 512x512, batched over 4)
// 32x64 tile, BK=16, 256 threads, 2x4 acc. grid = (8, 16, 4).
// ---------------------------------------------------------------------------
__global__ __launch_bounds__(256) void out_gemm(
    const float* __restrict__ Aa, const float* __restrict__ Bh,
    float* __restrict__ Co)
{
    const int bz = blockIdx.z;
    const float* A  = Aa + ((size_t)bz << 18);
    const float* Bm = Bh + ((size_t)bz << 18);
    float*       C  = Co + ((size_t)bz << 18);
    const int m0 = blockIdx.y * 32;
    const int n0 = blockIdx.x * 64;

    __shared__ __attribute__((aligned(16))) float As[16][36];
    __shared__ __attribute__((aligned(16))) float Bs[16][68];

    const int tid  = threadIdx.x;
    const int tr   = tid >> 4;
    const int tc   = tid & 15;
    const int la_r = tid >> 3;
    const int la_c = (tid & 7) << 1;
    const int lb_r = tid >> 4;
    const int lb_c = (tid & 15) << 2;

    float acc[2][4] = {};

    for (int k0 = 0; k0 < 512; k0 += 16) {
        float2 a2 = *(const float2*)(A + (size_t)(m0 + la_r) * 512 + k0 + la_c);
        float4 b4 = *(const float4*)(Bm + (size_t)(k0 + lb_r) * 512 + n0 + lb_c);
        __syncthreads();
        As[la_c + 0][la_r] = a2.x;
        As[la_c + 1][la_r] = a2.y;
        *(float4*)&Bs[lb_r][lb_c] = b4;
        __syncthreads();
        #pragma unroll
        for (int kk = 0; kk < 16; ++kk) {
            float2 av = *(const float2*)&As[kk][tr << 1];
            float4 bv = *(const float4*)&Bs[kk][tc << 2];
            const float* ap = (const float*)&av;
            const float* bp = (const float*)&bv;
            #pragma unroll
            for (int i = 0; i < 2; ++i)
                #pragma unroll
                for (int j = 0; j < 4; ++j)
                    acc[i][j] = fmaf(ap[i], bp[j], acc[i][j]);
        }
    }
    #pragma unroll
    for (int i = 0; i < 2; ++i) {
        float4 r = make_float4(acc[i][0], acc[i][1], acc[i][2], acc[i][3]);
        *(float4*)(C + (size_t)(m0 + (tr << 1) + i) * 512 + n0 + (tc << 2)) = r;
    }
}

// ---------------------------------------------------------------------------
extern "C" void kernel_launch(void* const* d_in, const int* in_sizes, int n_in,
                              void* d_out, int out_size, void* d_ws, size_t ws_size,
                              hipStream_t stream)
{
    const float* hq = (const float*)d_in[0];   // [4,512,512]
    const float* hp = (const float*)d_in[1];   // [4,512,512]
    const float* W1 = (const float*)d_in[2];   // [512,256]
    const float* W2 = (const float*)d_in[3];   // [512,256]
    const float* vv = (const float*)d_in[4];   // [256]
    float* out = (float*)d_out;                // [4,512,512]

    float* Eqp = (float*)d_ws;                 // [2048,256]  2MB
    float* Epp = Eqp + 2048 * VDIM;            // [2048,256]  2MB
    float* aa  = Epp + 2048 * VDIM;            // [2048,512]  4MB
    const size_t need = (size_t)(2048 * VDIM * 2 + 2048 * 512) * sizeof(float);

    proj_exp_gemm<<<dim3(4, 128), 256, 0, stream>>>(hq, hp, W1, W2, Eqp, Epp);

    if (ws_size >= need) {
        score_softmax<false><<<512, 256, 0, stream>>>(Eqp, Epp, vv, hq, aa, out);
        out_gemm<<<dim3(8, 16, 4), 256, 0, stream>>>(aa, hq, out);
    } else {
        score_softmax<true><<<512, 256, 0, stream>>>(Eqp, Epp, vv, hq, nullptr, out);
    }
}

// Round 3
// 91.447 us; speedup vs baseline: 1.4713x; 1.0138x over previous
//
#include <hip/hip_runtime.h>

// B=4, Q=512, P=512, Q_SIZE=512 (=DDIM), P_SIZE=512, V_SIZE=256 (=VDIM)
#define VDIM 256
#define DDIM 512
#define LOG2E     1.4426950408889634f
#define TWO_LOG2E 2.8853900817779268f

// ---------------------------------------------------------------------------
// K1: projections fused with exp:  Eq = exp(2*(hq@W1)),  Ep = exp(2*(hp@W2))
// 32x64 tile, BK=16, 256 threads, 2x4 acc/thread. grid = (4, 128).
// ---------------------------------------------------------------------------
__global__ __launch_bounds__(256) void proj_exp_gemm(
    const float* __restrict__ hq, const float* __restrict__ hp,
    const float* __restrict__ W1, const float* __restrict__ W2,
    float* __restrict__ Eq, float* __restrict__ Ep)
{
    const int by = blockIdx.y;            // 0..127: first 64 -> Eq, last 64 -> Ep
    const float *A, *W; float *C;
    if (by < 64) { A = hq; W = W1; C = Eq; }
    else         { A = hp; W = W2; C = Ep; }
    const int m0 = (by & 63) * 32;
    const int n0 = blockIdx.x * 64;

    __shared__ __attribute__((aligned(16))) float As[16][36];   // [k][m]
    __shared__ __attribute__((aligned(16))) float Bs[16][68];   // [k][n]

    const int tid  = threadIdx.x;
    const int tr   = tid >> 4;            // 0..15 -> rows tr*2..+1
    const int tc   = tid & 15;            // 0..15 -> cols tc*4..+3
    const int la_r = tid >> 3;            // 0..31
    const int la_c = (tid & 7) << 1;      // 0,2,..,14
    const int lb_r = tid >> 4;            // 0..15
    const int lb_c = (tid & 15) << 2;     // 0..60

    float acc[2][4] = {};

    for (int k0 = 0; k0 < 512; k0 += 16) {
        float2 a2 = *(const float2*)(A + (size_t)(m0 + la_r) * 512 + k0 + la_c);
        float4 b4 = *(const float4*)(W + (size_t)(k0 + lb_r) * VDIM + n0 + lb_c);
        __syncthreads();
        As[la_c + 0][la_r] = a2.x;
        As[la_c + 1][la_r] = a2.y;
        *(float4*)&Bs[lb_r][lb_c] = b4;
        __syncthreads();
        #pragma unroll
        for (int kk = 0; kk < 16; ++kk) {
            float2 av = *(const float2*)&As[kk][tr << 1];
            float4 bv = *(const float4*)&Bs[kk][tc << 2];
            const float* ap = (const float*)&av;
            const float* bp = (const float*)&bv;
            #pragma unroll
            for (int i = 0; i < 2; ++i)
                #pragma unroll
                for (int j = 0; j < 4; ++j)
                    acc[i][j] = fmaf(ap[i], bp[j], acc[i][j]);
        }
    }
    #pragma unroll
    for (int i = 0; i < 2; ++i) {
        float4 r;
        r.x = __builtin_amdgcn_exp2f(acc[i][0] * TWO_LOG2E);
        r.y = __builtin_amdgcn_exp2f(acc[i][1] * TWO_LOG2E);
        r.z = __builtin_amdgcn_exp2f(acc[i][2] * TWO_LOG2E);
        r.w = __builtin_amdgcn_exp2f(acc[i][3] * TWO_LOG2E);
        *(float4*)(C + (size_t)(m0 + (tr << 1) + i) * VDIM + n0 + (tc << 2)) = r;
    }
}

// ---------------------------------------------------------------------------
// K2: block = (b, 4 p-rows), 512 threads, thread t owns q=t.
// score term: v_j * tanh(sp+sq) -> (dropping softmax-invariant const)
//   -2 * v_j / (1 + Ep*Eq).  4-way rcp batching (exact algebra):
//   sum_{j=0..3} w_j/t_j = [ (w0 t1 + w1 t0) t2 t3 + (w2 t3 + w3 t2) t0 t1 ]
//                          / (t0 t1 t2 t3),   t_j = 1 + Ep_j*Eq_j
// => 14 VALU + 1 rcp per 4 terms.
// ---------------------------------------------------------------------------
template<bool FUSED>
__global__ __launch_bounds__(512) void score_softmax(
    const float* __restrict__ Eq, const float* __restrict__ Ep,
    const float* __restrict__ vvec, const float* __restrict__ hq,
    float* __restrict__ aout, float* __restrict__ out)
{
    const int blk = blockIdx.x;           // 0..511
    const int b   = blk >> 7;
    const int p0  = (blk & 127) << 2;

    __shared__ __attribute__((aligned(16))) float ep_s[4][VDIM];
    __shared__ __attribute__((aligned(16))) float vv_s[VDIM];
    __shared__ __attribute__((aligned(16))) float score[4][512];

    const int t = threadIdx.x;            // 0..511

    if (t < VDIM) vv_s[t] = vvec[t];
    {
        float* epf = &ep_s[0][0];         // 1024 floats, 2 per thread
        const int r0 = t >> 8;            // 0..1
        const int c0 = t & 255;
        epf[t]       = Ep[(size_t)((b << 9) + p0 + r0) * VDIM + c0];
        epf[t + 512] = Ep[(size_t)((b << 9) + p0 + 2 + r0) * VDIM + c0];
    }
    __syncthreads();

    // ---- phase 1: acc[pp] = sum_v v_j / (1 + Ep*Eq)  for q = t ----
    float acc[4] = {};
    const float4* eqr = (const float4*)(Eq + (size_t)((b << 9) + t) * VDIM);

    #pragma unroll 8
    for (int vi = 0; vi < VDIM / 4; ++vi) {
        const float4 e4 = eqr[vi];
        const float4 w4 = *(const float4*)&vv_s[vi << 2];
        #pragma unroll
        for (int pp = 0; pp < 4; ++pp) {
            const float4 p4 = *(const float4*)&ep_s[pp][vi << 2];
            const float t0 = fmaf(p4.x, e4.x, 1.f);
            const float t1 = fmaf(p4.y, e4.y, 1.f);
            const float t2 = fmaf(p4.z, e4.z, 1.f);
            const float t3 = fmaf(p4.w, e4.w, 1.f);
            const float d01 = t0 * t1;
            const float d23 = t2 * t3;
            const float den = d01 * d23;
            const float n01 = fmaf(w4.x, t1, w4.y * t0);
            const float n23 = fmaf(w4.z, t3, w4.w * t2);
            const float num = fmaf(n01, d23, n23 * d01);
            acc[pp] = fmaf(num, __builtin_amdgcn_rcpf(den), acc[pp]);
        }
    }
    #pragma unroll
    for (int pp = 0; pp < 4; ++pp) score[pp][t] = acc[pp];
    __syncthreads();

    // ---- phase 2: softmax over q (true score = const - 2*acc); waves 0-3 ----
    {
        const int wid = t >> 6, lane = t & 63;
        if (wid < 4) {
            float vals[8];
            float m = -1e30f;
            #pragma unroll
            for (int i = 0; i < 8; ++i) {
                vals[i] = -2.f * score[wid][lane + (i << 6)];
                m = fmaxf(m, vals[i]);
            }
            #pragma unroll
            for (int off = 32; off; off >>= 1) m = fmaxf(m, __shfl_xor(m, off));
            float sum = 0.f;
            #pragma unroll
            for (int i = 0; i < 8; ++i) {
                vals[i] = __builtin_amdgcn_exp2f((vals[i] - m) * LOG2E);
                sum += vals[i];
            }
            #pragma unroll
            for (int off = 32; off; off >>= 1) sum += __shfl_xor(sum, off);
            const float inv = __builtin_amdgcn_rcpf(sum);
            #pragma unroll
            for (int i = 0; i < 8; ++i) score[wid][lane + (i << 6)] = vals[i] * inv;
        }
    }
    __syncthreads();

    if (!FUSED) {
        // write a[b, p0+pp, :]  (float4-coalesced; 128 float4 per row)
        const int pp = t >> 7, c = t & 127;
        float4* arow = (float4*)(aout + (size_t)((b << 9) + p0 + pp) * 512);
        arow[c] = *(const float4*)&score[pp][c << 2];
    } else {
        // fallback phase 3: out[p, d=t] = sum_q a[p,q] * hq[q,t]
        float ax[4] = {};
        #pragma unroll 4
        for (int q = 0; q < 512; ++q) {
            const float h = hq[(size_t)((b << 9) + q) * DDIM + t];
            #pragma unroll
            for (int pp = 0; pp < 4; ++pp)
                ax[pp] = fmaf(score[pp][q], h, ax[pp]);
        }
        #pragma unroll
        for (int pp = 0; pp < 4; ++pp)
            out[(size_t)((b << 9) + p0 + pp) * DDIM + t] = ax[pp];
    }
}

// ---------------------------------------------------------------------------
// K3: out[b] = a[b] @ hq[b]   (512x512 @ 512x512, batched over 4)
// 32x64 tile, BK=16, 256 threads, 2x4 acc. grid = (8, 16, 4).
// ---------------------------------------------------------------------------
__global__ __launch_bounds__(256) void out_gemm(
    const float* __restrict__ Aa, const float* __restrict__ Bh,
    float* __restrict__ Co)
{
    const int bz = blockIdx.z;
    const float* A  = Aa + ((size_t)bz << 18);
    const float* Bm = Bh + ((size_t)bz << 18);
    float*       C  = Co + ((size_t)bz << 18);
    const int m0 = blockIdx.y * 32;
    const int n0 = blockIdx.x * 64;

    __shared__ __attribute__((aligned(16))) float As[16][36];
    __shared__ __attribute__((aligned(16))) float Bs[16][68];

    const int tid  = threadIdx.x;
    const int tr   = tid >> 4;
    const int tc   = tid & 15;
    const int la_r = tid >> 3;
    const int la_c = (tid & 7) << 1;
    const int lb_r = tid >> 4;
    const int lb_c = (tid & 15) << 2;

    float acc[2][4] = {};

    for (int k0 = 0; k0 < 512; k0 += 16) {
        float2 a2 = *(const float2*)(A + (size_t)(m0 + la_r) * 512 + k0 + la_c);
        float4 b4 = *(const float4*)(Bm + (size_t)(k0 + lb_r) * 512 + n0 + lb_c);
        __syncthreads();
        As[la_c + 0][la_r] = a2.x;
        As[la_c + 1][la_r] = a2.y;
        *(float4*)&Bs[lb_r][lb_c] = b4;
        __syncthreads();
        #pragma unroll
        for (int kk = 0; kk < 16; ++kk) {
            float2 av = *(const float2*)&As[kk][tr << 1];
            float4 bv = *(const float4*)&Bs[kk][tc << 2];
            const float* ap = (const float*)&av;
            const float* bp = (const float*)&bv;
            #pragma unroll
            for (int i = 0; i < 2; ++i)
                #pragma unroll
                for (int j = 0; j < 4; ++j)
                    acc[i][j] = fmaf(ap[i], bp[j], acc[i][j]);
        }
    }
    #pragma unroll
    for (int i = 0; i < 2; ++i) {
        float4 r = make_float4(acc[i][0], acc[i][1], acc[i][2], acc[i][3]);
        *(float4*)(C + (size_t)(m0 + (tr << 1) + i) * 512 + n0 + (tc << 2)) = r;
    }
}

// ---------------------------------------------------------------------------
extern "C" void kernel_launch(void* const* d_in, const int* in_sizes, int n_in,
                              void* d_out, int out_size, void* d_ws, size_t ws_size,
                              hipStream_t stream)
{
    const float* hq = (const float*)d_in[0];   // [4,512,512]
    const float* hp = (const float*)d_in[1];   // [4,512,512]
    const float* W1 = (const float*)d_in[2];   // [512,256]
    const float* W2 = (const float*)d_in[3];   // [512,256]
    const float* vv = (const float*)d_in[4];   // [256]
    float* out = (float*)d_out;                // [4,512,512]

    float* Eqp = (float*)d_ws;                 // [2048,256]  2MB
    float* Epp = Eqp + 2048 * VDIM;            // [2048,256]  2MB
    float* aa  = Epp + 2048 * VDIM;            // [2048,512]  4MB
    const size_t need = (size_t)(2048 * VDIM * 2 + 2048 * 512) * sizeof(float);

    proj_exp_gemm<<<dim3(4, 128), 256, 0, stream>>>(hq, hp, W1, W2, Eqp, Epp);

    if (ws_size >= need) {
        score_softmax<false><<<512, 512, 0, stream>>>(Eqp, Epp, vv, hq, aa, out);
        out_gemm<<<dim3(8, 16, 4), 256, 0, stream>>>(aa, hq, out);
    } else {
        score_softmax<true><<<512, 512, 0, stream>>>(Eqp, Epp, vv, hq, nullptr, out);
    }
}

// Round 4
// 82.700 us; speedup vs baseline: 1.6269x; 1.1058x over previous
//
#include <hip/hip_runtime.h>

// B=4, Q=512, P=512, Q_SIZE=512 (=DDIM), P_SIZE=512, V_SIZE=256 (=VDIM)
#define VDIM 256
#define DDIM 512
#define LOG2E     1.4426950408889634f
#define TWO_LOG2E 2.8853900817779268f

// ---------------------------------------------------------------------------
// K1: projections fused with exp.
//   Eq half: written TRANSPOSED v4-chunked:  EqT4[b][vi][q] (float4 over v)
//            so the score kernel's per-q reads are lane-coalesced.
//   Ep half: row-major [p][v] (read block-uniformly later).
// 32x64 tile, BK=16, 256 threads, 2x4 acc/thread. grid = (4, 128).
// ---------------------------------------------------------------------------
__global__ __launch_bounds__(256) void proj_exp_gemm(
    const float* __restrict__ hq, const float* __restrict__ hp,
    const float* __restrict__ W1, const float* __restrict__ W2,
    float* __restrict__ Eq, float* __restrict__ Ep)
{
    const int by = blockIdx.y;            // 0..127: first 64 -> Eq, last 64 -> Ep
    const float *A, *W;
    if (by < 64) { A = hq; W = W1; }
    else         { A = hp; W = W2; }
    const int m0 = (by & 63) * 32;        // row in [0,2048)
    const int n0 = blockIdx.x * 64;

    __shared__ __attribute__((aligned(16))) float As[16][36];   // [k][m]
    __shared__ __attribute__((aligned(16))) float Bs[16][68];   // [k][n]

    const int tid  = threadIdx.x;
    const int tr   = tid >> 4;            // 0..15 -> rows tr*2..+1
    const int tc   = tid & 15;            // 0..15 -> cols tc*4..+3
    const int la_r = tid >> 3;            // 0..31
    const int la_c = (tid & 7) << 1;      // 0,2,..,14
    const int lb_r = tid >> 4;            // 0..15
    const int lb_c = (tid & 15) << 2;     // 0..60

    float acc[2][4] = {};

    for (int k0 = 0; k0 < 512; k0 += 16) {
        float2 a2 = *(const float2*)(A + (size_t)(m0 + la_r) * 512 + k0 + la_c);
        float4 b4 = *(const float4*)(W + (size_t)(k0 + lb_r) * VDIM + n0 + lb_c);
        __syncthreads();
        As[la_c + 0][la_r] = a2.x;
        As[la_c + 1][la_r] = a2.y;
        *(float4*)&Bs[lb_r][lb_c] = b4;
        __syncthreads();
        #pragma unroll
        for (int kk = 0; kk < 16; ++kk) {
            float2 av = *(const float2*)&As[kk][tr << 1];
            float4 bv = *(const float4*)&Bs[kk][tc << 2];
            const float* ap = (const float*)&av;
            const float* bp = (const float*)&bv;
            #pragma unroll
            for (int i = 0; i < 2; ++i)
                #pragma unroll
                for (int j = 0; j < 4; ++j)
                    acc[i][j] = fmaf(ap[i], bp[j], acc[i][j]);
        }
    }

    if (by < 64) {
        // transposed v4-chunked write: EqT4[(b*64 + vi)*512 + q] = float4
        float4* EqT = (float4*)Eq;
        const int bb = m0 >> 9;
        const int qb = m0 & 511;
        const int vi = (blockIdx.x << 4) + tc;
        #pragma unroll
        for (int i = 0; i < 2; ++i) {
            float4 r;
            r.x = __builtin_amdgcn_exp2f(acc[i][0] * TWO_LOG2E);
            r.y = __builtin_amdgcn_exp2f(acc[i][1] * TWO_LOG2E);
            r.z = __builtin_amdgcn_exp2f(acc[i][2] * TWO_LOG2E);
            r.w = __builtin_amdgcn_exp2f(acc[i][3] * TWO_LOG2E);
            const int q = qb + (tr << 1) + i;
            EqT[((size_t)(bb << 6) + vi) * 512 + q] = r;
        }
    } else {
        #pragma unroll
        for (int i = 0; i < 2; ++i) {
            float4 r;
            r.x = __builtin_amdgcn_exp2f(acc[i][0] * TWO_LOG2E);
            r.y = __builtin_amdgcn_exp2f(acc[i][1] * TWO_LOG2E);
            r.z = __builtin_amdgcn_exp2f(acc[i][2] * TWO_LOG2E);
            r.w = __builtin_amdgcn_exp2f(acc[i][3] * TWO_LOG2E);
            *(float4*)(Ep + (size_t)(m0 + (tr << 1) + i) * VDIM + n0 + (tc << 2)) = r;
        }
    }
}

// ---------------------------------------------------------------------------
// K2: block = (b, 2 p-rows), 512 threads, thread t owns q=t. grid = 1024.
// Eq read coalesced from EqT4[b][vi][q]; Ep/v read with BLOCK-UNIFORM
// addresses straight from global (scalarizes to s_load / 1-line broadcast;
// no LDS traffic). 4-way rcp batching as before:
//   sum_j w_j/t_j = [ (w0 t1 + w1 t0) t2 t3 + (w2 t3 + w3 t2) t0 t1 ] / (t0t1t2t3)
// ---------------------------------------------------------------------------
template<bool FUSED>
__global__ __launch_bounds__(512) void score_softmax(
    const float4* __restrict__ EqT, const float* __restrict__ Ep,
    const float* __restrict__ vvec, const float* __restrict__ hq,
    float* __restrict__ aout, float* __restrict__ out)
{
    const int blk = blockIdx.x;           // 0..1023
    const int b   = blk >> 8;
    const int p0  = (blk & 255) << 1;

    __shared__ __attribute__((aligned(16))) float score[2][512];
    const int t = threadIdx.x;            // q = t

    const float4* __restrict__ ep0 = (const float4*)(Ep + (size_t)((b << 9) + p0) * VDIM);
    const float4* __restrict__ ep1 = ep0 + (VDIM / 4);
    const float4* __restrict__ wv  = (const float4*)vvec;
    const float4* __restrict__ eq  = EqT + (((size_t)b << 6) << 9) + t;

    float acc0 = 0.f, acc1 = 0.f;
    #pragma unroll 8
    for (int vi = 0; vi < 64; ++vi) {
        const float4 e = eq[vi << 9];     // coalesced: lane-stride 16B
        const float4 w = wv[vi];          // uniform
        {
            const float4 p = ep0[vi];     // uniform
            const float t0 = fmaf(p.x, e.x, 1.f);
            const float t1 = fmaf(p.y, e.y, 1.f);
            const float t2 = fmaf(p.z, e.z, 1.f);
            const float t3 = fmaf(p.w, e.w, 1.f);
            const float d01 = t0 * t1, d23 = t2 * t3;
            const float den = d01 * d23;
            const float n01 = fmaf(w.x, t1, w.y * t0);
            const float n23 = fmaf(w.z, t3, w.w * t2);
            const float num = fmaf(n01, d23, n23 * d01);
            acc0 = fmaf(num, __builtin_amdgcn_rcpf(den), acc0);
        }
        {
            const float4 p = ep1[vi];     // uniform
            const float t0 = fmaf(p.x, e.x, 1.f);
            const float t1 = fmaf(p.y, e.y, 1.f);
            const float t2 = fmaf(p.z, e.z, 1.f);
            const float t3 = fmaf(p.w, e.w, 1.f);
            const float d01 = t0 * t1, d23 = t2 * t3;
            const float den = d01 * d23;
            const float n01 = fmaf(w.x, t1, w.y * t0);
            const float n23 = fmaf(w.z, t3, w.w * t2);
            const float num = fmaf(n01, d23, n23 * d01);
            acc1 = fmaf(num, __builtin_amdgcn_rcpf(den), acc1);
        }
    }
    score[0][t] = acc0;
    score[1][t] = acc1;
    __syncthreads();

    // softmax over q (true score = const - 2*acc); waves 0-1, one per p-row
    {
        const int wid = t >> 6, lane = t & 63;
        if (wid < 2) {
            float vals[8];
            float m = -1e30f;
            #pragma unroll
            for (int i = 0; i < 8; ++i) {
                vals[i] = -2.f * score[wid][lane + (i << 6)];
                m = fmaxf(m, vals[i]);
            }
            #pragma unroll
            for (int off = 32; off; off >>= 1) m = fmaxf(m, __shfl_xor(m, off));
            float sum = 0.f;
            #pragma unroll
            for (int i = 0; i < 8; ++i) {
                vals[i] = __builtin_amdgcn_exp2f((vals[i] - m) * LOG2E);
                sum += vals[i];
            }
            #pragma unroll
            for (int off = 32; off; off >>= 1) sum += __shfl_xor(sum, off);
            const float inv = __builtin_amdgcn_rcpf(sum);
            #pragma unroll
            for (int i = 0; i < 8; ++i) score[wid][lane + (i << 6)] = vals[i] * inv;
        }
    }
    __syncthreads();

    if (!FUSED) {
        if (t < 256) {
            const int pp = t >> 7, c = t & 127;
            float4* arow = (float4*)(aout + (size_t)((b << 9) + p0 + pp) * 512);
            arow[c] = *(const float4*)&score[pp][c << 2];
        }
    } else {
        float ax0 = 0.f, ax1 = 0.f;
        #pragma unroll 4
        for (int q = 0; q < 512; ++q) {
            const float h = hq[(size_t)((b << 9) + q) * DDIM + t];
            ax0 = fmaf(score[0][q], h, ax0);
            ax1 = fmaf(score[1][q], h, ax1);
        }
        out[(size_t)((b << 9) + p0)     * DDIM + t] = ax0;
        out[(size_t)((b << 9) + p0 + 1) * DDIM + t] = ax1;
    }
}

// ---------------------------------------------------------------------------
// K3: out[b] = a[b] @ hq[b]   (512x512 @ 512x512, batched over 4)
// 32x64 tile, BK=16, 256 threads, 2x4 acc. grid = (8, 16, 4).
// ---------------------------------------------------------------------------
__global__ __launch_bounds__(256) void out_gemm(
    const float* __restrict__ Aa, const float* __restrict__ Bh,
    float* __restrict__ Co)
{
    const int bz = blockIdx.z;
    const float* A  = Aa + ((size_t)bz << 18);
    const float* Bm = Bh + ((size_t)bz << 18);
    float*       C  = Co + ((size_t)bz << 18);
    const int m0 = blockIdx.y * 32;
    const int n0 = blockIdx.x * 64;

    __shared__ __attribute__((aligned(16))) float As[16][36];
    __shared__ __attribute__((aligned(16))) float Bs[16][68];

    const int tid  = threadIdx.x;
    const int tr   = tid >> 4;
    const int tc   = tid & 15;
    const int la_r = tid >> 3;
    const int la_c = (tid & 7) << 1;
    const int lb_r = tid >> 4;
    const int lb_c = (tid & 15) << 2;

    float acc[2][4] = {};

    for (int k0 = 0; k0 < 512; k0 += 16) {
        float2 a2 = *(const float2*)(A + (size_t)(m0 + la_r) * 512 + k0 + la_c);
        float4 b4 = *(const float4*)(Bm + (size_t)(k0 + lb_r) * 512 + n0 + lb_c);
        __syncthreads();
        As[la_c + 0][la_r] = a2.x;
        As[la_c + 1][la_r] = a2.y;
        *(float4*)&Bs[lb_r][lb_c] = b4;
        __syncthreads();
        #pragma unroll
        for (int kk = 0; kk < 16; ++kk) {
            float2 av = *(const float2*)&As[kk][tr << 1];
            float4 bv = *(const float4*)&Bs[kk][tc << 2];
            const float* ap = (const float*)&av;
            const float* bp = (const float*)&bv;
            #pragma unroll
            for (int i = 0; i < 2; ++i)
                #pragma unroll
                for (int j = 0; j < 4; ++j)
                    acc[i][j] = fmaf(ap[i], bp[j], acc[i][j]);
        }
    }
    #pragma unroll
    for (int i = 0; i < 2; ++i) {
        float4 r = make_float4(acc[i][0], acc[i][1], acc[i][2], acc[i][3]);
        *(float4*)(C + (size_t)(m0 + (tr << 1) + i) * 512 + n0 + (tc << 2)) = r;
    }
}

// ---------------------------------------------------------------------------
extern "C" void kernel_launch(void* const* d_in, const int* in_sizes, int n_in,
                              void* d_out, int out_size, void* d_ws, size_t ws_size,
                              hipStream_t stream)
{
    const float* hq = (const float*)d_in[0];   // [4,512,512]
    const float* hp = (const float*)d_in[1];   // [4,512,512]
    const float* W1 = (const float*)d_in[2];   // [512,256]
    const float* W2 = (const float*)d_in[3];   // [512,256]
    const float* vv = (const float*)d_in[4];   // [256]
    float* out = (float*)d_out;                // [4,512,512]

    float* Eqp = (float*)d_ws;                 // EqT4 [4][64][512] float4 = 2MB
    float* Epp = Eqp + 2048 * VDIM;            // [2048,256]  2MB
    float* aa  = Epp + 2048 * VDIM;            // [2048,512]  4MB
    const size_t need = (size_t)(2048 * VDIM * 2 + 2048 * 512) * sizeof(float);

    proj_exp_gemm<<<dim3(4, 128), 256, 0, stream>>>(hq, hp, W1, W2, Eqp, Epp);

    if (ws_size >= need) {
        score_softmax<false><<<1024, 512, 0, stream>>>((const float4*)Eqp, Epp, vv, hq, aa, out);
        out_gemm<<<dim3(8, 16, 4), 256, 0, stream>>>(aa, hq, out);
    } else {
        score_softmax<true><<<1024, 512, 0, stream>>>((const float4*)Eqp, Epp, vv, hq, nullptr, out);
    }
}